// Round 5
// baseline (989.907 us; speedup 1.0000x reference)
//
#include <hip/hip_runtime.h>
#include <cstddef>
#include <cstdint>

// ---------------------------------------------------------------------------
// LogicRecursiveNN — Round 5: 8-phase 256^2 deep-pipelined GEMM (T2+T3+T4+T5)
// for the 4 big dispatches (L0 G1 gather, L0 G2, L1 G1, L2 G1 = 74% of FLOPs);
// proven 128^2 m97-structure kernel for tail levels / one2one / head.
//
// 8-phase schedule (derived via region-lifetime analysis; constants match the
// verified m201 template: vmcnt(6) at phases 4&8, 7 half-tiles prologue):
//   iter i computes tiles t=2i (buf0, phases 1-4) and t+1 (buf1, phases 5-8).
//   P1: RD all A+B frags of buf0 (24 ds_read_b128); stage Bh1(t+1)->buf1
//   P2: stage Ah0(t+2)->buf0      P3: stage Ah1(t+2)
//   P4: stage Bh0(t+2); vmcnt(6)  P5: RD buf1; stage Bh1(t+2)
//   P6: stage Ah0(t+3)->buf1      P7: stage Ah1(t+3)
//   P8: stage Bh0(t+3); vmcnt(6)
//   each phase: [reads][stage][vmcnt?] barrier, setprio(1), 16 MFMA,
//   setprio(0), barrier.  Last iteration peeled (no prefetch, vmcnt(0)@P4).
// ---------------------------------------------------------------------------

typedef _Float16 f16;
typedef _Float16 f16x8 __attribute__((ext_vector_type(8)));
typedef float f32x4 __attribute__((ext_vector_type(4)));

__device__ __forceinline__ void gll16(const void* g, void* l) {
  __builtin_amdgcn_global_load_lds(
      (const __attribute__((address_space(1))) void*)g,
      (__attribute__((address_space(3))) void*)l, 16, 0, 0);
}

#define BAR __builtin_amdgcn_s_barrier()
#define VM6 asm volatile("s_waitcnt vmcnt(6)" ::: "memory")
#define VM0 asm volatile("s_waitcnt vmcnt(0)" ::: "memory")

// ---------------- 8-phase 256x256 kernel (BK=64, 8 waves, LDS 128 KiB) -----
// C[M,N] = relu(A[M,K] @ Bt[N,K]^T + bias), f16 in/out, f32 accum.
// M,N multiples of 256; K multiple of 128 (K in {1024,2048} here).
// GATHER: A row r = entf[lidx[2r + (k>>9)]][k&511]  (requires K==1024).
template <int GATHER>
__global__ __launch_bounds__(512) void gemm8(
    const f16* __restrict__ A, const f16* __restrict__ Bt,
    const float* __restrict__ bias, f16* __restrict__ C, int N, int K,
    const int* __restrict__ lidx, const f16* __restrict__ entf) {
  __shared__ __align__(16) f16 As[2][2][128][64];  // [buf][half][row][col]
  __shared__ __align__(16) f16 Bs[2][2][128][64];
  const int tid = threadIdx.x;
  const int m0 = blockIdx.y * 256;
  const int n0 = blockIdx.x * 256;

  // staging map: op covers 64 rows; row = tid>>3, chunk = tid&7 (16B).
  // LDS dest linear (wave base + lane*16); source k-chunk pre-swizzled so a
  // read at chunk c ^ (row&7) returns logical chunk c (both-sides involution).
  const int srow = tid >> 3;                        // 0..63
  const int sk = ((tid & 7) ^ (srow & 7)) << 3;     // f16 elems
  const int wvb = (tid >> 6) * 1024;                // wave LDS byte base
  const f16* Asrc = GATHER ? (const f16*)nullptr
                           : (A + (size_t)(m0 + srow) * K + sk);
  const f16* Bsrc = Bt + (size_t)(n0 + srow) * K + sk;

  int eA0[2][2], eA1[2][2];  // [half][op] leaf entities (literal-indexed)
  if (GATHER) {
#pragma unroll
    for (int hh = 0; hh < 2; ++hh)
#pragma unroll
      for (int oo = 0; oo < 2; ++oo) {
        const int grow = m0 + hh * 128 + oo * 64 + srow;
        eA0[hh][oo] = lidx[2 * grow];
        eA1[hh][oo] = lidx[2 * grow + 1];
      }
  }

#define STAGE_A(BUF, HALF, KB)                                          \
  {                                                                     \
    char* d_ = (char*)&As[BUF][HALF][0][0] + wvb;                       \
    if (!GATHER) {                                                      \
      const f16* s_ = Asrc + (size_t)((HALF)*128) * K + (KB);           \
      gll16(s_, d_);                                                    \
      gll16(s_ + (size_t)64 * K, d_ + 8192);                            \
    } else {                                                            \
      const int hs_ = (KB) >> 9;                                        \
      const int kk_ = ((KB)&511) + sk;                                  \
      const int e0_ = hs_ ? eA1[HALF][0] : eA0[HALF][0];                \
      const int e1_ = hs_ ? eA1[HALF][1] : eA0[HALF][1];                \
      gll16(entf + ((size_t)e0_ << 9) + kk_, d_);                       \
      gll16(entf + ((size_t)e1_ << 9) + kk_, d_ + 8192);                \
    }                                                                   \
  }
#define STAGE_B(BUF, HALF, KB)                                          \
  {                                                                     \
    char* d_ = (char*)&Bs[BUF][HALF][0][0] + wvb;                       \
    const f16* s_ = Bsrc + (size_t)((HALF)*128) * K + (KB);             \
    gll16(s_, d_);                                                      \
    gll16(s_ + (size_t)64 * K, d_ + 8192);                              \
  }

  // fragment map: 8 waves 2M x 4N; wave owns 128x64 (8 m-frags x 4 n-frags)
  const int l = tid & 63, wid = tid >> 6;
  const int wm = wid >> 2, wn = wid & 3;
  const int q = l & 15, kg = l >> 4;
  const char* Ard = (const char*)&As[0][wm][0][0] + q * 128;
  const char* Brd = (const char*)&Bs[0][wn >> 1][0][0] + ((wn & 1) * 64 + q) * 128;
  const int csw = (kg << 4) ^ ((q & 7) << 4);  // swizzled byte col, ks=0

  f16x8 a[8][2], b[4][2];
  f32x4 acc[8][4] = {};

#define RD_AB(BUF)                                                          \
  {                                                                         \
    _Pragma("unroll") for (int i_ = 0; i_ < 8; ++i_) {                      \
      a[i_][0] = *(const f16x8*)(Ard + (BUF)*32768 + i_ * 2048 + csw);      \
      a[i_][1] = *(const f16x8*)(Ard + (BUF)*32768 + i_ * 2048 + (csw ^ 64)); \
    }                                                                       \
    _Pragma("unroll") for (int j_ = 0; j_ < 4; ++j_) {                      \
      b[j_][0] = *(const f16x8*)(Brd + (BUF)*32768 + j_ * 2048 + csw);      \
      b[j_][1] = *(const f16x8*)(Brd + (BUF)*32768 + j_ * 2048 + (csw ^ 64)); \
    }                                                                       \
  }
#define MM(MLO, KS)                                                         \
  __builtin_amdgcn_s_setprio(1);                                            \
  {                                                                         \
    _Pragma("unroll") for (int i_ = 0; i_ < 4; ++i_) {                      \
      _Pragma("unroll") for (int j_ = 0; j_ < 4; ++j_) {                    \
        acc[(MLO)*4 + i_][j_] = __builtin_amdgcn_mfma_f32_16x16x32_f16(     \
            a[(MLO)*4 + i_][KS], b[j_][KS], acc[(MLO)*4 + i_][j_], 0, 0, 0); \
      }                                                                     \
    }                                                                       \
  }                                                                         \
  __builtin_amdgcn_s_setprio(0);

  // ---- prologue: tile0 full + tile1 {Ah0,Ah1,Bh0} = 7 half-tiles (14 ops)
  STAGE_A(0, 0, 0); STAGE_A(0, 1, 0); STAGE_B(0, 0, 0); STAGE_B(0, 1, 0);
  STAGE_A(1, 0, 64); STAGE_A(1, 1, 64); STAGE_B(1, 0, 64);
  VM6; BAR;

  const int niter = K >> 7;
  int kb = 0;
  for (int it = 0; it < niter - 1; ++it, kb += 128) {
    const int t1 = kb + 64, t2 = kb + 128, t3 = kb + 192;
    RD_AB(0); STAGE_B(1, 1, t1);      BAR; MM(0, 0); BAR;  // P1
    STAGE_A(0, 0, t2);                BAR; MM(1, 0); BAR;  // P2
    STAGE_A(0, 1, t2);                BAR; MM(0, 1); BAR;  // P3
    STAGE_B(0, 0, t2);           VM6; BAR; MM(1, 1); BAR;  // P4
    RD_AB(1); STAGE_B(0, 1, t2);      BAR; MM(0, 0); BAR;  // P5
    STAGE_A(1, 0, t3);                BAR; MM(1, 0); BAR;  // P6
    STAGE_A(1, 1, t3);                BAR; MM(0, 1); BAR;  // P7
    STAGE_B(1, 0, t3);           VM6; BAR; MM(1, 1); BAR;  // P8
  }
  {  // ---- peeled last iteration: no prefetch
    const int t1 = kb + 64;
    RD_AB(0); STAGE_B(1, 1, t1);      BAR; MM(0, 0); BAR;  // P1
                                      BAR; MM(1, 0); BAR;  // P2
                                      BAR; MM(0, 1); BAR;  // P3
                                 VM0; BAR; MM(1, 1); BAR;  // P4
    RD_AB(1);                         BAR; MM(0, 0); BAR;  // P5
                                      BAR; MM(1, 0); BAR;  // P6
                                      BAR; MM(0, 1); BAR;  // P7
                                      BAR; MM(1, 1); BAR;  // P8
  }
#undef STAGE_A
#undef STAGE_B
#undef RD_AB
#undef MM

  // ---- epilogue: row = wm*128 + i*16 + kg*4 + vi, col = wn*64 + j*16 + q
#pragma unroll
  for (int j = 0; j < 4; ++j) {
    const int col = n0 + wn * 64 + j * 16 + q;
    const float bsv = bias[col];
#pragma unroll
    for (int i = 0; i < 8; ++i) {
      f32x4 v = acc[i][j];
#pragma unroll
      for (int vi = 0; vi < 4; ++vi) {
        const int row = m0 + wm * 128 + i * 16 + kg * 4 + vi;
        float c = fmaxf(v[vi] + bsv, 0.0f);
        C[(size_t)row * N + col] = (f16)c;
      }
    }
  }
}

// ---------------- 128x128 m97-structure kernel (tail levels / head) --------
// ACT: 1=relu, 2=tanh. OUTF32: store float. M,N mult of 128; K mult of 64.
template <int ACT, int OUTF32>
__global__ __launch_bounds__(256) void gemm128(
    const f16* __restrict__ A, const f16* __restrict__ Bt,
    const float* __restrict__ bias, void* __restrict__ Cout, int N, int K) {
  __shared__ __align__(16) f16 As[128 * 64];
  __shared__ __align__(16) f16 Bs[128 * 64];
  const int tid = threadIdx.x;
  const int m0 = blockIdx.y * 128;
  const int n0 = blockIdx.x * 128;
  const int srow = tid >> 3;
  const int sk = ((tid & 7) ^ ((tid >> 3) & 7)) << 3;
  const f16* Ag = A + (size_t)(m0 + srow) * K + sk;
  const f16* Bg = Bt + (size_t)(n0 + srow) * K + sk;
  char* Al = (char*)As + (tid >> 6) * 1024;
  char* Bl = (char*)Bs + (tid >> 6) * 1024;
  const int l = tid & 63;
  const int wm = tid >> 7;
  const int wn = (tid >> 6) & 1;
  const int q = l & 15;
  const int kg = l >> 4;
  const char* Ar = (const char*)As + (wm * 64 + q) * 128;
  const char* Br = (const char*)Bs + (wn * 64 + q) * 128;
  const int c0 = ((kg << 4) ^ ((q & 7) << 4));
  f32x4 acc[4][4] = {};
  for (int k0 = 0; k0 < K; k0 += 64) {
#pragma unroll
    for (int r = 0; r < 4; ++r) {
      gll16(Ag + (size_t)(r * 32) * K + k0, Al + r * 4096);
      gll16(Bg + (size_t)(r * 32) * K + k0, Bl + r * 4096);
    }
    __syncthreads();
#pragma unroll
    for (int ks = 0; ks < 2; ++ks) {
      const int cb = c0 ^ (ks << 6);
      f16x8 a[4], b[4];
#pragma unroll
      for (int i = 0; i < 4; ++i) a[i] = *(const f16x8*)(Ar + i * 2048 + cb);
#pragma unroll
      for (int j = 0; j < 4; ++j) b[j] = *(const f16x8*)(Br + j * 2048 + cb);
#pragma unroll
      for (int i = 0; i < 4; ++i)
#pragma unroll
        for (int j = 0; j < 4; ++j)
          acc[i][j] = __builtin_amdgcn_mfma_f32_16x16x32_f16(a[i], b[j],
                                                             acc[i][j], 0, 0, 0);
    }
    __syncthreads();
  }
#pragma unroll
  for (int j = 0; j < 4; ++j) {
    const int col = n0 + wn * 64 + j * 16 + q;
    const float bsv = bias[col];
#pragma unroll
    for (int i = 0; i < 4; ++i) {
      f32x4 v = acc[i][j];
#pragma unroll
      for (int vi = 0; vi < 4; ++vi) {
        const int row = m0 + wm * 64 + i * 16 + kg * 4 + vi;
        float c = v[vi] + bsv;
        if (ACT == 1) c = fmaxf(c, 0.0f);
        if (ACT == 2) c = tanhf(c);
        if (OUTF32)
          ((float*)Cout)[(size_t)row * N + col] = c;
        else
          ((f16*)Cout)[(size_t)row * N + col] = (f16)c;
      }
    }
  }
}

// dst[n][k] = (f16) src[k][n];  K,N multiples of 32
__global__ void transpose_cvt(const float* __restrict__ src,
                              f16* __restrict__ dst, int K, int N) {
  __shared__ f16 tile[32][33];
  const int k0 = blockIdx.x * 32, n0 = blockIdx.y * 32;
  const int tx = threadIdx.x & 31, ty = threadIdx.x >> 5;
  for (int r = ty; r < 32; r += 8)
    tile[r][tx] = (f16)src[(size_t)(k0 + r) * N + n0 + tx];
  __syncthreads();
  for (int r = ty; r < 32; r += 8)
    dst[(size_t)(n0 + r) * K + k0 + tx] = tile[tx][r];
}

// f32 -> f16 elementwise, 8 per thread
__global__ void cvt_f16(const float* __restrict__ src, f16* __restrict__ dst) {
  const int g = blockIdx.x * 256 + threadIdx.x;
  const float4* s = (const float4*)(src + (size_t)g * 8);
  float4 v0 = s[0], v1 = s[1];
  f16x8 o;
  o[0] = (f16)v0.x; o[1] = (f16)v0.y; o[2] = (f16)v0.z; o[3] = (f16)v0.w;
  o[4] = (f16)v1.x; o[5] = (f16)v1.y; o[6] = (f16)v1.z; o[7] = (f16)v1.w;
  *(f16x8*)(dst + (size_t)g * 8) = o;
}

__global__ void build_feat_h(const float* __restrict__ th,
                             const f16* __restrict__ root,
                             f16* __restrict__ feat) {
  int idx = blockIdx.x * 256 + threadIdx.x;  // 512*1536 total
  int b = idx / 1536;
  int c = idx - b * 1536;
  feat[idx] = (c < 512) ? (f16)th[c] : root[(size_t)b * 1024 + (c - 512)];
}

__global__ void head_final(const float* __restrict__ z3,
                           const float* __restrict__ h4,
                           const float* __restrict__ hb4,
                           float* __restrict__ out) {
  int row = blockIdx.x;
  int t = threadIdx.x;  // 64
  float v = z3[(size_t)row * 128 + t] * h4[t] +
            z3[(size_t)row * 128 + 64 + t] * h4[64 + t];
#pragma unroll
  for (int off = 32; off; off >>= 1) v += __shfl_down(v, off);
  if (t == 0) out[row] = 1.0f / (1.0f + expf(-(v + hb4[0])));
}

extern "C" void kernel_launch(void* const* d_in, const int* in_sizes, int n_in,
                              void* d_out, int out_size, void* d_ws,
                              size_t ws_size, hipStream_t stream) {
  const int* leaf_idx = (const int*)d_in[0];
  const float* ent_emb = (const float*)d_in[1];
  const float* th_emb = (const float*)d_in[2];
  const float* w1 = (const float*)d_in[3];
  const float* b1 = (const float*)d_in[4];
  const float* w2 = (const float*)d_in[5];
  const float* b2 = (const float*)d_in[6];
  const float* o1 = (const float*)d_in[7];
  const float* ob1 = (const float*)d_in[8];
  const float* o2 = (const float*)d_in[9];
  const float* ob2 = (const float*)d_in[10];
  const float* h1 = (const float*)d_in[11];
  const float* hb1 = (const float*)d_in[12];
  const float* h2 = (const float*)d_in[13];
  const float* hb2 = (const float*)d_in[14];
  const float* h3 = (const float*)d_in[15];
  const float* hb3 = (const float*)d_in[16];
  const float* h4 = (const float*)d_in[17];
  const float* hb4 = (const float*)d_in[18];
  float* out = (float*)d_out;

  char* p = (char*)d_ws;
  f16* w1t = (f16*)p;  p += (size_t)2048 * 1024 * 2;
  f16* w2t = (f16*)p;  p += (size_t)512 * 2048 * 2;
  f16* o1t = (f16*)p;  p += (size_t)2048 * 512 * 2;
  f16* o2t = (f16*)p;  p += (size_t)512 * 2048 * 2;
  f16* h1t = (f16*)p;  p += (size_t)512 * 1536 * 2;
  f16* h2t = (f16*)p;  p += (size_t)256 * 512 * 2;
  f16* h3t = (f16*)p;  p += (size_t)128 * 256 * 2;
  f16* entf = (f16*)p; p += (size_t)2000 * 512 * 2;
  f16* Hf   = (f16*)p; p += (size_t)32768 * 2048 * 2;  // 128 MB
  f16* bufA = (f16*)p; p += (size_t)32768 * 512 * 2;   // 32 MB
  f16* featf = (f16*)p; p += (size_t)512 * 1536 * 2;
  f16* z1h  = (f16*)p; p += (size_t)512 * 512 * 2;
  f16* z2h  = (f16*)p; p += (size_t)512 * 256 * 2;
  float* z3 = (float*)p; p += (size_t)512 * 128 * 4;
  // bufB lives in Hf's top half (Hf live region per level <= 64 MB there):
  f16* bufB = Hf + (size_t)32 * 1024 * 1024;  // byte offset 64 MB
  // total ws ~= 177 MB

  // ---- prep
  transpose_cvt<<<dim3(1024 / 32, 2048 / 32), 256, 0, stream>>>(w1, w1t, 1024, 2048);
  transpose_cvt<<<dim3(2048 / 32, 512 / 32), 256, 0, stream>>>(w2, w2t, 2048, 512);
  transpose_cvt<<<dim3(512 / 32, 2048 / 32), 256, 0, stream>>>(o1, o1t, 512, 2048);
  transpose_cvt<<<dim3(2048 / 32, 512 / 32), 256, 0, stream>>>(o2, o2t, 2048, 512);
  transpose_cvt<<<dim3(1536 / 32, 512 / 32), 256, 0, stream>>>(h1, h1t, 1536, 512);
  transpose_cvt<<<dim3(512 / 32, 256 / 32), 256, 0, stream>>>(h2, h2t, 512, 256);
  transpose_cvt<<<dim3(256 / 32, 128 / 32), 256, 0, stream>>>(h3, h3t, 256, 128);
  cvt_f16<<<(2000 * 512) / 2048, 256, 0, stream>>>(ent_emb, entf);

  // ---- tree levels
  // L0 (M=32768): gather GEMM1 (8-phase) -> Hf[0:128MB]; GEMM2 (8-phase) -> bufA
  gemm8<1><<<dim3(8, 128), 512, 0, stream>>>(nullptr, w1t, b1, Hf, 2048, 1024,
                                             leaf_idx, entf);
  gemm8<0><<<dim3(2, 128), 512, 0, stream>>>(Hf, w2t, b2, bufA, 512, 2048,
                                             nullptr, nullptr);
  // L1 (M=16384): GEMM1 8-phase -> Hf[0:64MB]; GEMM2 128^2 -> bufB (@Hf+64MB)
  gemm8<0><<<dim3(8, 64), 512, 0, stream>>>(bufA, w1t, b1, Hf, 2048, 1024,
                                            nullptr, nullptr);
  gemm128<1, 0><<<dim3(4, 128), 256, 0, stream>>>(Hf, w2t, b2, bufB, 512, 2048);
  // L2 (M=8192): GEMM1 8-phase -> Hf[0:32MB]; GEMM2 -> bufA
  gemm8<0><<<dim3(8, 32), 512, 0, stream>>>(bufB, w1t, b1, Hf, 2048, 1024,
                                            nullptr, nullptr);
  gemm128<1, 0><<<dim3(4, 64), 256, 0, stream>>>(Hf, w2t, b2, bufA, 512, 2048);
  // L3 (M=4096)
  gemm128<1, 0><<<dim3(16, 32), 256, 0, stream>>>(bufA, w1t, b1, Hf, 2048, 1024);
  gemm128<1, 0><<<dim3(4, 32), 256, 0, stream>>>(Hf, w2t, b2, bufB, 512, 2048);
  // L4 (M=2048)
  gemm128<1, 0><<<dim3(16, 16), 256, 0, stream>>>(bufB, w1t, b1, Hf, 2048, 1024);
  gemm128<1, 0><<<dim3(4, 16), 256, 0, stream>>>(Hf, w2t, b2, bufA, 512, 2048);
  // L5 (M=1024)
  gemm128<1, 0><<<dim3(16, 8), 256, 0, stream>>>(bufA, w1t, b1, Hf, 2048, 1024);
  gemm128<1, 0><<<dim3(4, 8), 256, 0, stream>>>(Hf, w2t, b2, bufB, 512, 2048);

  // ---- one2one: relu(root@o1) -> tanh(..@o2); root=bufB[1024,512]
  gemm128<1, 0><<<dim3(16, 8), 256, 0, stream>>>(bufB, o1t, ob1, Hf, 2048, 512);
  gemm128<2, 0><<<dim3(4, 8), 256, 0, stream>>>(Hf, o2t, ob2, bufA, 512, 2048);

  // ---- head (f16 MFMA), rootf = bufA [1024,512]
  build_feat_h<<<(512 * 1536) / 256, 256, 0, stream>>>(th_emb, bufA, featf);
  gemm128<1, 0><<<dim3(4, 4), 256, 0, stream>>>(featf, h1t, hb1, z1h, 512, 1536);
  gemm128<1, 0><<<dim3(2, 4), 256, 0, stream>>>(z1h, h2t, hb2, z2h, 256, 512);
  gemm128<1, 1><<<dim3(1, 4), 256, 0, stream>>>(z2h, h3t, hb3, z3, 128, 256);
  head_final<<<512, 64, 0, stream>>>(z3, h4, hb4, out);
}

// Round 7
// 897.231 us; speedup vs baseline: 1.1033x; 1.1033x over previous
//
#include <hip/hip_runtime.h>
#include <cstddef>
#include <cstdint>

// ---------------------------------------------------------------------------
// LogicRecursiveNN — Round 7 == Round 6 resubmit (R6 was an infra timeout).
// Register-safe deep-pipelined 256^2 GEMM: BK=32 ring-of-3 LDS buffers so
// only 12 fragments (48 VGPR) are live per phase; __launch_bounds__(512,2)
// for the 256-VGPR cap.  Schedule per 2 tiles (4 phases):
//   P1: RD(buf[t%3]) 12 ds_read; stage A0,A1(t+2); bar; MM(0) 16 MFMA; bar
//   P2: stage B0,B1(t+2); vmcnt(4) [drains t+1's 4 ops, leaves t+2's]; bar;
//       MM(1); bar
// Ring-of-3 region safety: buf[(t+2)%3] was last read at tile t-1's P1,
// fully drained (MFMA data-dep) two barriers before restaging.
// gemm128 (R4, proven) kept for tail levels / one2one / head.
// ---------------------------------------------------------------------------

typedef _Float16 f16;
typedef _Float16 f16x8 __attribute__((ext_vector_type(8)));
typedef float f32x4 __attribute__((ext_vector_type(4)));

__device__ __forceinline__ void gll16(const void* g, void* l) {
  __builtin_amdgcn_global_load_lds(
      (const __attribute__((address_space(1))) void*)g,
      (__attribute__((address_space(3))) void*)l, 16, 0, 0);
}

#define BAR __builtin_amdgcn_s_barrier()
#define VM4 asm volatile("s_waitcnt vmcnt(4)" ::: "memory")
#define VM0 asm volatile("s_waitcnt vmcnt(0)" ::: "memory")

// C[M,N] = relu(A[M,K] @ Bt[N,K]^T + bias), f16 in/out, f32 accum.
// M,N multiples of 256; K multiple of 128.  GATHER (K==1024): A row r =
// entf[lidx[2r + (k>>9)]][k&511].
template <int GATHER>
__global__ __launch_bounds__(512, 2) void gemm4(
    const f16* __restrict__ A, const f16* __restrict__ Bt,
    const float* __restrict__ bias, f16* __restrict__ C, int N, int K,
    const int* __restrict__ lidx, const f16* __restrict__ entf) {
  __shared__ __align__(16) f16 As[3][256][32];  // 48 KB, ring of 3 K-tiles
  __shared__ __align__(16) f16 Bs[3][256][32];  // 48 KB
  const int tid = threadIdx.x;
  const int m0 = blockIdx.y * 256;
  const int n0 = blockIdx.x * 256;

  // ---- staging: one op = 512 lanes x 16B = 8 KB = 128 rows x 64 B.
  // thread -> (srow = tid>>2, chunk = tid&3); source chunk pre-swizzled with
  // f(r) = (r&3)^((r>>2)&3) so a read at chunk kg ^ f(row) is logical kg.
  const int srow = tid >> 2;  // 0..127
  const int fs = (((tid & 3) ^ ((srow & 3) ^ ((srow >> 2) & 3)))) << 3;
  const f16* Asrc = GATHER ? (const f16*)nullptr
                           : (A + (size_t)(m0 + srow) * K + fs);
  const f16* Bsrc = Bt + (size_t)(n0 + srow) * K + fs;
  const int wvb = (tid >> 6) * 1024;  // wave's 16-row slice within an op

  int eh0[2], eh1[2];  // gather entities, op half h in {0,1}
  if (GATHER) {
#pragma unroll
    for (int h = 0; h < 2; ++h) {
      const int grow = m0 + h * 128 + srow;
      eh0[h] = lidx[2 * grow];
      eh1[h] = lidx[2 * grow + 1];
    }
  }

#define STAGE_A(S, H, KB)                                              \
  {                                                                    \
    char* d_ = (char*)As + (size_t)(S)*16384 + (H)*8192 + wvb;         \
    if (!GATHER) {                                                     \
      gll16(Asrc + (size_t)(H)*128 * K + (KB), d_);                    \
    } else {                                                           \
      const int e_ = ((KB) >> 9) ? eh1[H] : eh0[H];                    \
      gll16(entf + ((size_t)e_ << 9) + (((KB)&511) + fs), d_);         \
    }                                                                  \
  }
#define STAGE_B(S, H, KB)                                              \
  {                                                                    \
    char* d_ = (char*)Bs + (size_t)(S)*16384 + (H)*8192 + wvb;         \
    gll16(Bsrc + (size_t)(H)*128 * K + (KB), d_);                      \
  }

  // ---- fragments: 8 waves 2M x 4N; wave owns 128x64 = 8 m-frags x 4 n-frags
  const int l = tid & 63, wid = tid >> 6;
  const int wm = wid >> 2, wn = wid & 3;
  const int q = l & 15, kg = l >> 4;
  const int fq = (q & 3) ^ ((q >> 2) & 3);
  const int csw = (kg ^ fq) << 4;  // swizzled byte col within 64 B row
  const char* Ard = (const char*)As + (wm * 128 + q) * 64 + csw;
  const char* Brd = (const char*)Bs + (wn * 64 + q) * 64 + csw;

  f16x8 a[8], b[4];
  f32x4 acc[8][4] = {};

#define RD(S)                                                          \
  {                                                                    \
    _Pragma("unroll") for (int i_ = 0; i_ < 8; ++i_)                   \
        a[i_] = *(const f16x8*)(Ard + (S)*16384 + i_ * 1024);          \
    _Pragma("unroll") for (int j_ = 0; j_ < 4; ++j_)                   \
        b[j_] = *(const f16x8*)(Brd + (S)*16384 + j_ * 1024);          \
  }
#define MM(MLO)                                                        \
  __builtin_amdgcn_s_setprio(1);                                       \
  {                                                                    \
    _Pragma("unroll") for (int i_ = 0; i_ < 4; ++i_) {                 \
      _Pragma("unroll") for (int j_ = 0; j_ < 4; ++j_) {               \
        acc[(MLO)*4 + i_][j_] = __builtin_amdgcn_mfma_f32_16x16x32_f16( \
            a[(MLO)*4 + i_], b[j_], acc[(MLO)*4 + i_][j_], 0, 0, 0);   \
      }                                                                \
    }                                                                  \
  }                                                                    \
  __builtin_amdgcn_s_setprio(0);

  // ---- prologue: stage tiles 0 and 1 (8 ops); wait tile0 (first 4)
  STAGE_A(0, 0, 0); STAGE_A(0, 1, 0); STAGE_B(0, 0, 0); STAGE_B(0, 1, 0);
  STAGE_A(1, 0, 32); STAGE_A(1, 1, 32); STAGE_B(1, 0, 32); STAGE_B(1, 1, 32);
  VM4; BAR;

  const int nt = K >> 5;
  int s = 0;  // t % 3
  for (int t = 0; t < nt; ++t) {
    const int s2 = (s + 2 >= 3) ? (s - 1) : (s + 2);  // (t+2) % 3
    const int kb2 = (t + 2) << 5;
    const bool pf = (t + 2) < nt;
    // P1: read current tile's fragments; prefetch A halves of t+2
    RD(s);
    if (pf) { STAGE_A(s2, 0, kb2); STAGE_A(s2, 1, kb2); }
    BAR; MM(0); BAR;
    // P2: prefetch B halves of t+2; counted drain for t+1
    if (pf) {
      STAGE_B(s2, 0, kb2); STAGE_B(s2, 1, kb2);
      VM4;  // drains t+1's 4 ops, leaves t+2's 4 in flight
    } else {
      VM0;
    }
    BAR; MM(1); BAR;
    s = (s + 1 == 3) ? 0 : (s + 1);
  }
#undef STAGE_A
#undef STAGE_B
#undef RD
#undef MM

  // ---- epilogue: row = wm*128 + i*16 + kg*4 + vi, col = wn*64 + j*16 + q
#pragma unroll
  for (int j = 0; j < 4; ++j) {
    const int col = n0 + wn * 64 + j * 16 + q;
    const float bsv = bias[col];
#pragma unroll
    for (int i = 0; i < 8; ++i) {
      f32x4 v = acc[i][j];
#pragma unroll
      for (int vi = 0; vi < 4; ++vi) {
        const int row = m0 + wm * 128 + i * 16 + kg * 4 + vi;
        C[(size_t)row * N + col] = (f16)fmaxf(v[vi] + bsv, 0.0f);
      }
    }
  }
}

// ---------------- 128x128 m97-structure kernel (tail levels / head) --------
template <int ACT, int OUTF32>
__global__ __launch_bounds__(256) void gemm128(
    const f16* __restrict__ A, const f16* __restrict__ Bt,
    const float* __restrict__ bias, void* __restrict__ Cout, int N, int K) {
  __shared__ __align__(16) f16 As[128 * 64];
  __shared__ __align__(16) f16 Bs[128 * 64];
  const int tid = threadIdx.x;
  const int m0 = blockIdx.y * 128;
  const int n0 = blockIdx.x * 128;
  const int srow = tid >> 3;
  const int sk = ((tid & 7) ^ ((tid >> 3) & 7)) << 3;
  const f16* Ag = A + (size_t)(m0 + srow) * K + sk;
  const f16* Bg = Bt + (size_t)(n0 + srow) * K + sk;
  char* Al = (char*)As + (tid >> 6) * 1024;
  char* Bl = (char*)Bs + (tid >> 6) * 1024;
  const int l = tid & 63;
  const int wm = tid >> 7;
  const int wn = (tid >> 6) & 1;
  const int q = l & 15;
  const int kg = l >> 4;
  const char* Ar = (const char*)As + (wm * 64 + q) * 128;
  const char* Br = (const char*)Bs + (wn * 64 + q) * 128;
  const int c0 = ((kg << 4) ^ ((q & 7) << 4));
  f32x4 acc[4][4] = {};
  for (int k0 = 0; k0 < K; k0 += 64) {
#pragma unroll
    for (int r = 0; r < 4; ++r) {
      gll16(Ag + (size_t)(r * 32) * K + k0, Al + r * 4096);
      gll16(Bg + (size_t)(r * 32) * K + k0, Bl + r * 4096);
    }
    __syncthreads();
#pragma unroll
    for (int ks = 0; ks < 2; ++ks) {
      const int cb = c0 ^ (ks << 6);
      f16x8 a[4], b[4];
#pragma unroll
      for (int i = 0; i < 4; ++i) a[i] = *(const f16x8*)(Ar + i * 2048 + cb);
#pragma unroll
      for (int j = 0; j < 4; ++j) b[j] = *(const f16x8*)(Br + j * 2048 + cb);
#pragma unroll
      for (int i = 0; i < 4; ++i)
#pragma unroll
        for (int j = 0; j < 4; ++j)
          acc[i][j] = __builtin_amdgcn_mfma_f32_16x16x32_f16(a[i], b[j],
                                                             acc[i][j], 0, 0, 0);
    }
    __syncthreads();
  }
#pragma unroll
  for (int j = 0; j < 4; ++j) {
    const int col = n0 + wn * 64 + j * 16 + q;
    const float bsv = bias[col];
#pragma unroll
    for (int i = 0; i < 4; ++i) {
      f32x4 v = acc[i][j];
#pragma unroll
      for (int vi = 0; vi < 4; ++vi) {
        const int row = m0 + wm * 64 + i * 16 + kg * 4 + vi;
        float c = v[vi] + bsv;
        if (ACT == 1) c = fmaxf(c, 0.0f);
        if (ACT == 2) c = tanhf(c);
        if (OUTF32)
          ((float*)Cout)[(size_t)row * N + col] = c;
        else
          ((f16*)Cout)[(size_t)row * N + col] = (f16)c;
      }
    }
  }
}

// dst[n][k] = (f16) src[k][n];  K,N multiples of 32
__global__ void transpose_cvt(const float* __restrict__ src,
                              f16* __restrict__ dst, int K, int N) {
  __shared__ f16 tile[32][33];
  const int k0 = blockIdx.x * 32, n0 = blockIdx.y * 32;
  const int tx = threadIdx.x & 31, ty = threadIdx.x >> 5;
  for (int r = ty; r < 32; r += 8)
    tile[r][tx] = (f16)src[(size_t)(k0 + r) * N + n0 + tx];
  __syncthreads();
  for (int r = ty; r < 32; r += 8)
    dst[(size_t)(n0 + r) * K + k0 + tx] = tile[tx][r];
}

// f32 -> f16 elementwise, 8 per thread
__global__ void cvt_f16(const float* __restrict__ src, f16* __restrict__ dst) {
  const int g = blockIdx.x * 256 + threadIdx.x;
  const float4* s = (const float4*)(src + (size_t)g * 8);
  float4 v0 = s[0], v1 = s[1];
  f16x8 o;
  o[0] = (f16)v0.x; o[1] = (f16)v0.y; o[2] = (f16)v0.z; o[3] = (f16)v0.w;
  o[4] = (f16)v1.x; o[5] = (f16)v1.y; o[6] = (f16)v1.z; o[7] = (f16)v1.w;
  *(f16x8*)(dst + (size_t)g * 8) = o;
}

__global__ void build_feat_h(const float* __restrict__ th,
                             const f16* __restrict__ root,
                             f16* __restrict__ feat) {
  int idx = blockIdx.x * 256 + threadIdx.x;  // 512*1536 total
  int b = idx / 1536;
  int c = idx - b * 1536;
  feat[idx] = (c < 512) ? (f16)th[c] : root[(size_t)b * 1024 + (c - 512)];
}

__global__ void head_final(const float* __restrict__ z3,
                           const float* __restrict__ h4,
                           const float* __restrict__ hb4,
                           float* __restrict__ out) {
  int row = blockIdx.x;
  int t = threadIdx.x;  // 64
  float v = z3[(size_t)row * 128 + t] * h4[t] +
            z3[(size_t)row * 128 + 64 + t] * h4[64 + t];
#pragma unroll
  for (int off = 32; off; off >>= 1) v += __shfl_down(v, off);
  if (t == 0) out[row] = 1.0f / (1.0f + expf(-(v + hb4[0])));
}

extern "C" void kernel_launch(void* const* d_in, const int* in_sizes, int n_in,
                              void* d_out, int out_size, void* d_ws,
                              size_t ws_size, hipStream_t stream) {
  const int* leaf_idx = (const int*)d_in[0];
  const float* ent_emb = (const float*)d_in[1];
  const float* th_emb = (const float*)d_in[2];
  const float* w1 = (const float*)d_in[3];
  const float* b1 = (const float*)d_in[4];
  const float* w2 = (const float*)d_in[5];
  const float* b2 = (const float*)d_in[6];
  const float* o1 = (const float*)d_in[7];
  const float* ob1 = (const float*)d_in[8];
  const float* o2 = (const float*)d_in[9];
  const float* ob2 = (const float*)d_in[10];
  const float* h1 = (const float*)d_in[11];
  const float* hb1 = (const float*)d_in[12];
  const float* h2 = (const float*)d_in[13];
  const float* hb2 = (const float*)d_in[14];
  const float* h3 = (const float*)d_in[15];
  const float* hb3 = (const float*)d_in[16];
  const float* h4 = (const float*)d_in[17];
  const float* hb4 = (const float*)d_in[18];
  float* out = (float*)d_out;

  char* p = (char*)d_ws;
  f16* w1t = (f16*)p;  p += (size_t)2048 * 1024 * 2;
  f16* w2t = (f16*)p;  p += (size_t)512 * 2048 * 2;
  f16* o1t = (f16*)p;  p += (size_t)2048 * 512 * 2;
  f16* o2t = (f16*)p;  p += (size_t)512 * 2048 * 2;
  f16* h1t = (f16*)p;  p += (size_t)512 * 1536 * 2;
  f16* h2t = (f16*)p;  p += (size_t)256 * 512 * 2;
  f16* h3t = (f16*)p;  p += (size_t)128 * 256 * 2;
  f16* entf = (f16*)p; p += (size_t)2000 * 512 * 2;
  f16* Hf   = (f16*)p; p += (size_t)32768 * 2048 * 2;  // 128 MB
  f16* bufA = (f16*)p; p += (size_t)32768 * 512 * 2;   // 32 MB
  f16* featf = (f16*)p; p += (size_t)512 * 1536 * 2;
  f16* z1h  = (f16*)p; p += (size_t)512 * 512 * 2;
  f16* z2h  = (f16*)p; p += (size_t)512 * 256 * 2;
  float* z3 = (float*)p; p += (size_t)512 * 128 * 4;
  // bufB overlays Hf's top half (per-level live region of Hf <= 64 MB then)
  f16* bufB = Hf + (size_t)32 * 1024 * 1024;

  // ---- prep
  transpose_cvt<<<dim3(1024 / 32, 2048 / 32), 256, 0, stream>>>(w1, w1t, 1024, 2048);
  transpose_cvt<<<dim3(2048 / 32, 512 / 32), 256, 0, stream>>>(w2, w2t, 2048, 512);
  transpose_cvt<<<dim3(512 / 32, 2048 / 32), 256, 0, stream>>>(o1, o1t, 512, 2048);
  transpose_cvt<<<dim3(2048 / 32, 512 / 32), 256, 0, stream>>>(o2, o2t, 2048, 512);
  transpose_cvt<<<dim3(1536 / 32, 512 / 32), 256, 0, stream>>>(h1, h1t, 1536, 512);
  transpose_cvt<<<dim3(512 / 32, 256 / 32), 256, 0, stream>>>(h2, h2t, 512, 256);
  transpose_cvt<<<dim3(256 / 32, 128 / 32), 256, 0, stream>>>(h3, h3t, 256, 128);
  cvt_f16<<<(2000 * 512) / 2048, 256, 0, stream>>>(ent_emb, entf);

  // ---- tree levels
  // L0 (M=32768): gather GEMM1 -> Hf (128 MB); GEMM2 -> bufA
  gemm4<1><<<dim3(8, 128), 512, 0, stream>>>(nullptr, w1t, b1, Hf, 2048, 1024,
                                             leaf_idx, entf);
  gemm4<0><<<dim3(2, 128), 512, 0, stream>>>(Hf, w2t, b2, bufA, 512, 2048,
                                             nullptr, nullptr);
  // L1 (M=16384): GEMM1 -> Hf[0:64MB]; GEMM2 (128^2) -> bufB (@Hf+64MB)
  gemm4<0><<<dim3(8, 64), 512, 0, stream>>>(bufA, w1t, b1, Hf, 2048, 1024,
                                            nullptr, nullptr);
  gemm128<1, 0><<<dim3(4, 128), 256, 0, stream>>>(Hf, w2t, b2, bufB, 512, 2048);
  // L2 (M=8192): GEMM1 -> Hf[0:32MB]; GEMM2 -> bufA
  gemm4<0><<<dim3(8, 32), 512, 0, stream>>>(bufB, w1t, b1, Hf, 2048, 1024,
                                            nullptr, nullptr);
  gemm128<1, 0><<<dim3(4, 64), 256, 0, stream>>>(Hf, w2t, b2, bufA, 512, 2048);
  // L3 (M=4096)
  gemm128<1, 0><<<dim3(16, 32), 256, 0, stream>>>(bufA, w1t, b1, Hf, 2048, 1024);
  gemm128<1, 0><<<dim3(4, 32), 256, 0, stream>>>(Hf, w2t, b2, bufB, 512, 2048);
  // L4 (M=2048)
  gemm128<1, 0><<<dim3(16, 16), 256, 0, stream>>>(bufB, w1t, b1, Hf, 2048, 1024);
  gemm128<1, 0><<<dim3(4, 16), 256, 0, stream>>>(Hf, w2t, b2, bufA, 512, 2048);
  // L5 (M=1024)
  gemm128<1, 0><<<dim3(16, 8), 256, 0, stream>>>(bufA, w1t, b1, Hf, 2048, 1024);
  gemm128<1, 0><<<dim3(4, 8), 256, 0, stream>>>(Hf, w2t, b2, bufB, 512, 2048);

  // ---- one2one: relu(root@o1) -> tanh(..@o2); root = bufB [1024,512]
  gemm128<1, 0><<<dim3(16, 8), 256, 0, stream>>>(bufB, o1t, ob1, Hf, 2048, 512);
  gemm128<2, 0><<<dim3(4, 8), 256, 0, stream>>>(Hf, o2t, ob2, bufA, 512, 2048);

  // ---- head (f16 MFMA), root f16 = bufA [1024,512]
  build_feat_h<<<(512 * 1536) / 256, 256, 0, stream>>>(th_emb, bufA, featf);
  gemm128<1, 0><<<dim3(4, 4), 256, 0, stream>>>(featf, h1t, hb1, z1h, 512, 1536);
  gemm128<1, 0><<<dim3(2, 4), 256, 0, stream>>>(z1h, h2t, hb2, z2h, 256, 512);
  gemm128<1, 1><<<dim3(1, 4), 256, 0, stream>>>(z2h, h3t, hb3, z3, 128, 256);
  head_final<<<512, 64, 0, stream>>>(z3, h4, hb4, out);
}

// Round 8
// 832.107 us; speedup vs baseline: 1.1896x; 1.0783x over previous
//
#include <hip/hip_runtime.h>
#include <cstddef>
#include <cstdint>

// ---------------------------------------------------------------------------
// LogicRecursiveNN — Round 8: 256^2 8-phase GEMM with REGION-SCHEDULED stages
// and per-phase fragment reads (the R5/R7 spill fix).
//   - BK=64, 128B LDS rows, R4/R5-proven swizzle (0 bank conflicts measured).
//   - Per K-tile (4 phases): P1 reads ALL b-frags (8xb128) + a_lo ks0 (4),
//     P2/P3/P4 read 4 a-frags each -> <=48 frag VGPRs live (vs R5's 96).
//   - Region lifetimes: A(buf) read P1-P4 of its tile; B(buf) read only at P1.
//     Stages target regions >=1 barrier after their last read:
//       P1:A0(t1) P2:A1(t1) P3:B0(t2) P4:B1(t2) P5:A0(t2) P6:A1(t2)
//       P7:B0(t3) P8:B1(t3);  vmcnt(4) at P4 & P8 (2 half-tiles in flight).
//   - __launch_bounds__(512,1): hipcc treats arg2 as min blocks/CU (R7
//     evidence: (512,2) -> 128-VGPR cap); 1 block -> 256-VGPR cap. LDS=128KB
//     forces 1 block/CU regardless.
// gemm128 (R4, proven) for tail levels / one2one / head.
// ---------------------------------------------------------------------------

typedef _Float16 f16;
typedef _Float16 f16x8 __attribute__((ext_vector_type(8)));
typedef float f32x4 __attribute__((ext_vector_type(4)));

__device__ __forceinline__ void gll16(const void* g, void* l) {
  __builtin_amdgcn_global_load_lds(
      (const __attribute__((address_space(1))) void*)g,
      (__attribute__((address_space(3))) void*)l, 16, 0, 0);
}

#define BAR __builtin_amdgcn_s_barrier()
#define VM4 asm volatile("s_waitcnt vmcnt(4)" ::: "memory")
#define VM0 asm volatile("s_waitcnt vmcnt(0)" ::: "memory")

// C[M,N] = relu(A[M,K] @ Bt[N,K]^T + bias), f16 in/out, f32 accum.
// M,N multiples of 256; K multiple of 128 (K in {1024,2048} here).
// GATHER (K==1024): A row r = entf[lidx[2r + (k>>9)]][k&511].
template <int GATHER>
__global__ __launch_bounds__(512, 1) void gemm256(
    const f16* __restrict__ A, const f16* __restrict__ Bt,
    const float* __restrict__ bias, f16* __restrict__ C, int N, int K,
    const int* __restrict__ lidx, const f16* __restrict__ entf) {
  __shared__ __align__(16) f16 As[2][2][128][64];  // [buf][mhalf][row][k] 64KB
  __shared__ __align__(16) f16 Bs[2][2][128][64];  // [buf][nhalf][row][k] 64KB
  const int tid = threadIdx.x;
  const int m0 = blockIdx.y * 256;
  const int n0 = blockIdx.x * 256;

  // ---- staging: one op = 512 thr x 16B = 8KB = 64 rows x 128B.
  // A half-tile (128 rows x 64 k) = 2 ops. Source chunk pre-swizzled with
  // chunk ^ (row&7) so a read at cb ^ ((row&7)<<4) returns logical cb
  // (both-sides involution; R4/R5-proven, 0 conflicts).
  const int srow = tid >> 3;                     // 0..63
  const int sk = ((tid & 7) ^ (srow & 7)) << 3;  // f16 elems
  const f16* Asrc = GATHER ? (const f16*)nullptr
                           : (A + (size_t)(m0 + srow) * K + sk);
  const f16* Bsrc = Bt + (size_t)(n0 + srow) * K + sk;
  const int wvb = (tid >> 6) * 1024;  // wave base; HW adds lane*16

  int e0[2][2], e1[2][2];  // [mhalf][64-row group], literal-indexed
  if (GATHER) {
#pragma unroll
    for (int h = 0; h < 2; ++h)
#pragma unroll
      for (int o = 0; o < 2; ++o) {
        const int grow = m0 + h * 128 + o * 64 + srow;
        e0[h][o] = lidx[2 * grow];
        e1[h][o] = lidx[2 * grow + 1];
      }
  }

#define SA(BUF, HALF, KB)                                               \
  {                                                                     \
    char* d_ = (char*)&As[BUF][HALF][0][0] + wvb;                       \
    if (!GATHER) {                                                      \
      const f16* s_ = Asrc + (size_t)((HALF)*128) * K + (KB);           \
      gll16(s_, d_);                                                    \
      gll16(s_ + (size_t)64 * K, d_ + 8192);                            \
    } else {                                                            \
      const int hs_ = (KB) >> 9;                                        \
      const int kk_ = ((KB)&511) + sk;                                  \
      const int ea_ = hs_ ? e1[HALF][0] : e0[HALF][0];                  \
      const int eb_ = hs_ ? e1[HALF][1] : e0[HALF][1];                  \
      gll16(entf + ((size_t)ea_ << 9) + kk_, d_);                       \
      gll16(entf + ((size_t)eb_ << 9) + kk_, d_ + 8192);                \
    }                                                                   \
  }
#define SB(BUF, HALF, KB)                                               \
  {                                                                     \
    char* d_ = (char*)&Bs[BUF][HALF][0][0] + wvb;                       \
    const f16* s_ = Bsrc + (size_t)((HALF)*128) * K + (KB);             \
    gll16(s_, d_);                                                      \
    gll16(s_ + (size_t)64 * K, d_ + 8192);                              \
  }

  // ---- fragments: 8 waves 2M x 4N; wave owns 128x64 = 8 m-frags x 4 n-frags
  const int l = tid & 63, wid = tid >> 6;
  const int wm = wid >> 2, wn = wid & 3;
  const int q = l & 15, kg = l >> 4;
  const int csw = (kg << 4) ^ ((q & 7) << 4);  // swizzled byte col, ks=0
  const char* Abase = (const char*)As + wm * 16384 + q * 128;
  const char* Bbase =
      (const char*)Bs + (wn >> 1) * 16384 + ((wn & 1) * 64 + q) * 128;

  f16x8 a[4], b[4][2];
  f32x4 acc[8][4] = {};

#define RD_B(BUF)                                                       \
  {                                                                     \
    _Pragma("unroll") for (int j_ = 0; j_ < 4; ++j_) {                  \
      b[j_][0] = *(const f16x8*)(Bbase + (BUF)*32768 + j_ * 2048 + csw);       \
      b[j_][1] = *(const f16x8*)(Bbase + (BUF)*32768 + j_ * 2048 + (csw ^ 64)); \
    }                                                                   \
  }
#define RD_A(BUF, HI, KS)                                               \
  {                                                                     \
    _Pragma("unroll") for (int i_ = 0; i_ < 4; ++i_)                    \
        a[i_] = *(const f16x8*)(Abase + (BUF)*32768 +                   \
                                ((HI)*4 + i_) * 2048 + (csw ^ ((KS) << 6))); \
  }
#define MM(HI, KS)                                                      \
  __builtin_amdgcn_s_setprio(1);                                        \
  {                                                                     \
    _Pragma("unroll") for (int i_ = 0; i_ < 4; ++i_) {                  \
      _Pragma("unroll") for (int j_ = 0; j_ < 4; ++j_) {                \
        acc[(HI)*4 + i_][j_] = __builtin_amdgcn_mfma_f32_16x16x32_f16(  \
            a[i_], b[j_][KS], acc[(HI)*4 + i_][j_], 0, 0, 0);           \
      }                                                                 \
    }                                                                   \
  }                                                                     \
  __builtin_amdgcn_s_setprio(0);

  // ---- prologue: t0 full (8 ops) + t1's B halves (4 ops); vmcnt(4) -> t0
  // landed, t1-B in flight.
  SA(0, 0, 0); SA(0, 1, 0); SB(0, 0, 0); SB(0, 1, 0);
  SB(1, 0, 64); SB(1, 1, 64);
  VM4; BAR;

  const int niter = K >> 7;  // 2 K-tiles (of 64) per iter
  for (int it = 0; it < niter; ++it) {
    const int kt1 = (2 * it + 1) << 6;
    const int kt2 = (2 * it + 2) << 6;
    const int kt3 = (2 * it + 3) << 6;
    const bool pf = (it + 1) < niter;
    // P1: all b(buf0) + a_lo ks0; stage A0(t1) [As[1][0] last read prev P7]
    RD_B(0); RD_A(0, 0, 0); SA(1, 0, kt1);            BAR; MM(0, 0); BAR;
    // P2: a_hi ks0; stage A1(t1) [last read prev P8]
    RD_A(0, 1, 0); SA(1, 1, kt1);                     BAR; MM(1, 0); BAR;
    // P3: a_lo ks1; stage B0(t2) [Bs[0][0] read only at P1]
    RD_A(0, 0, 1); if (pf) SB(0, 0, kt2);             BAR; MM(0, 1); BAR;
    // P4: a_hi ks1; stage B1(t2); drain through A1(t1) (leave t2-B in flight)
    RD_A(0, 1, 1); if (pf) SB(0, 1, kt2);
    if (pf) { VM4; } else { VM0; }                    BAR; MM(1, 1); BAR;
    // P5: all b(buf1) + a_lo ks0; stage A0(t2) [As[0][0] read P1-P4, done]
    RD_B(1); RD_A(1, 0, 0); if (pf) SA(0, 0, kt2);    BAR; MM(0, 0); BAR;
    // P6: a_hi ks0; stage A1(t2)
    RD_A(1, 1, 0); if (pf) SA(0, 1, kt2);             BAR; MM(1, 0); BAR;
    // P7: a_lo ks1; stage B0(t3) [Bs[1][0] read only at P5]
    RD_A(1, 0, 1); if (pf) SB(1, 0, kt3);             BAR; MM(0, 1); BAR;
    // P8: a_hi ks1; stage B1(t3); drain through A1(t2)
    RD_A(1, 1, 1); if (pf) { SB(1, 1, kt3); VM4; }    BAR; MM(1, 1); BAR;
  }
#undef SA
#undef SB
#undef RD_B
#undef RD_A
#undef MM

  // ---- epilogue: row = wm*128 + i*16 + kg*4 + vi, col = wn*64 + j*16 + q
#pragma unroll
  for (int j = 0; j < 4; ++j) {
    const int col = n0 + wn * 64 + j * 16 + q;
    const float bsv = bias[col];
#pragma unroll
    for (int i = 0; i < 8; ++i) {
      f32x4 v = acc[i][j];
#pragma unroll
      for (int vi = 0; vi < 4; ++vi) {
        const int row = m0 + wm * 128 + i * 16 + kg * 4 + vi;
        C[(size_t)row * N + col] = (f16)fmaxf(v[vi] + bsv, 0.0f);
      }
    }
  }
}

// ---------------- 128x128 m97-structure kernel (tail levels / head) --------
template <int ACT, int OUTF32>
__global__ __launch_bounds__(256) void gemm128(
    const f16* __restrict__ A, const f16* __restrict__ Bt,
    const float* __restrict__ bias, void* __restrict__ Cout, int N, int K) {
  __shared__ __align__(16) f16 As[128 * 64];
  __shared__ __align__(16) f16 Bs[128 * 64];
  const int tid = threadIdx.x;
  const int m0 = blockIdx.y * 128;
  const int n0 = blockIdx.x * 128;
  const int srow = tid >> 3;
  const int sk = ((tid & 7) ^ ((tid >> 3) & 7)) << 3;
  const f16* Ag = A + (size_t)(m0 + srow) * K + sk;
  const f16* Bg = Bt + (size_t)(n0 + srow) * K + sk;
  char* Al = (char*)As + (tid >> 6) * 1024;
  char* Bl = (char*)Bs + (tid >> 6) * 1024;
  const int l = tid & 63;
  const int wm = tid >> 7;
  const int wn = (tid >> 6) & 1;
  const int q = l & 15;
  const int kg = l >> 4;
  const char* Ar = (const char*)As + (wm * 64 + q) * 128;
  const char* Br = (const char*)Bs + (wn * 64 + q) * 128;
  const int c0 = ((kg << 4) ^ ((q & 7) << 4));
  f32x4 acc[4][4] = {};
  for (int k0 = 0; k0 < K; k0 += 64) {
#pragma unroll
    for (int r = 0; r < 4; ++r) {
      gll16(Ag + (size_t)(r * 32) * K + k0, Al + r * 4096);
      gll16(Bg + (size_t)(r * 32) * K + k0, Bl + r * 4096);
    }
    __syncthreads();
#pragma unroll
    for (int ks = 0; ks < 2; ++ks) {
      const int cb = c0 ^ (ks << 6);
      f16x8 a[4], b[4];
#pragma unroll
      for (int i = 0; i < 4; ++i) a[i] = *(const f16x8*)(Ar + i * 2048 + cb);
#pragma unroll
      for (int j = 0; j < 4; ++j) b[j] = *(const f16x8*)(Br + j * 2048 + cb);
#pragma unroll
      for (int i = 0; i < 4; ++i)
#pragma unroll
        for (int j = 0; j < 4; ++j)
          acc[i][j] = __builtin_amdgcn_mfma_f32_16x16x32_f16(a[i], b[j],
                                                             acc[i][j], 0, 0, 0);
    }
    __syncthreads();
  }
#pragma unroll
  for (int j = 0; j < 4; ++j) {
    const int col = n0 + wn * 64 + j * 16 + q;
    const float bsv = bias[col];
#pragma unroll
    for (int i = 0; i < 4; ++i) {
      f32x4 v = acc[i][j];
#pragma unroll
      for (int vi = 0; vi < 4; ++vi) {
        const int row = m0 + wm * 64 + i * 16 + kg * 4 + vi;
        float c = v[vi] + bsv;
        if (ACT == 1) c = fmaxf(c, 0.0f);
        if (ACT == 2) c = tanhf(c);
        if (OUTF32)
          ((float*)Cout)[(size_t)row * N + col] = c;
        else
          ((f16*)Cout)[(size_t)row * N + col] = (f16)c;
      }
    }
  }
}

// dst[n][k] = (f16) src[k][n];  K,N multiples of 32
__global__ void transpose_cvt(const float* __restrict__ src,
                              f16* __restrict__ dst, int K, int N) {
  __shared__ f16 tile[32][33];
  const int k0 = blockIdx.x * 32, n0 = blockIdx.y * 32;
  const int tx = threadIdx.x & 31, ty = threadIdx.x >> 5;
  for (int r = ty; r < 32; r += 8)
    tile[r][tx] = (f16)src[(size_t)(k0 + r) * N + n0 + tx];
  __syncthreads();
  for (int r = ty; r < 32; r += 8)
    dst[(size_t)(n0 + r) * K + k0 + tx] = tile[tx][r];
}

// f32 -> f16 elementwise, 8 per thread
__global__ void cvt_f16(const float* __restrict__ src, f16* __restrict__ dst) {
  const int g = blockIdx.x * 256 + threadIdx.x;
  const float4* s = (const float4*)(src + (size_t)g * 8);
  float4 v0 = s[0], v1 = s[1];
  f16x8 o;
  o[0] = (f16)v0.x; o[1] = (f16)v0.y; o[2] = (f16)v0.z; o[3] = (f16)v0.w;
  o[4] = (f16)v1.x; o[5] = (f16)v1.y; o[6] = (f16)v1.z; o[7] = (f16)v1.w;
  *(f16x8*)(dst + (size_t)g * 8) = o;
}

__global__ void build_feat_h(const float* __restrict__ th,
                             const f16* __restrict__ root,
                             f16* __restrict__ feat) {
  int idx = blockIdx.x * 256 + threadIdx.x;  // 512*1536 total
  int b = idx / 1536;
  int c = idx - b * 1536;
  feat[idx] = (c < 512) ? (f16)th[c] : root[(size_t)b * 1024 + (c - 512)];
}

__global__ void head_final(const float* __restrict__ z3,
                           const float* __restrict__ h4,
                           const float* __restrict__ hb4,
                           float* __restrict__ out) {
  int row = blockIdx.x;
  int t = threadIdx.x;  // 64
  float v = z3[(size_t)row * 128 + t] * h4[t] +
            z3[(size_t)row * 128 + 64 + t] * h4[64 + t];
#pragma unroll
  for (int off = 32; off; off >>= 1) v += __shfl_down(v, off);
  if (t == 0) out[row] = 1.0f / (1.0f + expf(-(v + hb4[0])));
}

extern "C" void kernel_launch(void* const* d_in, const int* in_sizes, int n_in,
                              void* d_out, int out_size, void* d_ws,
                              size_t ws_size, hipStream_t stream) {
  const int* leaf_idx = (const int*)d_in[0];
  const float* ent_emb = (const float*)d_in[1];
  const float* th_emb = (const float*)d_in[2];
  const float* w1 = (const float*)d_in[3];
  const float* b1 = (const float*)d_in[4];
  const float* w2 = (const float*)d_in[5];
  const float* b2 = (const float*)d_in[6];
  const float* o1 = (const float*)d_in[7];
  const float* ob1 = (const float*)d_in[8];
  const float* o2 = (const float*)d_in[9];
  const float* ob2 = (const float*)d_in[10];
  const float* h1 = (const float*)d_in[11];
  const float* hb1 = (const float*)d_in[12];
  const float* h2 = (const float*)d_in[13];
  const float* hb2 = (const float*)d_in[14];
  const float* h3 = (const float*)d_in[15];
  const float* hb3 = (const float*)d_in[16];
  const float* h4 = (const float*)d_in[17];
  const float* hb4 = (const float*)d_in[18];
  float* out = (float*)d_out;

  char* p = (char*)d_ws;
  f16* w1t = (f16*)p;  p += (size_t)2048 * 1024 * 2;
  f16* w2t = (f16*)p;  p += (size_t)512 * 2048 * 2;
  f16* o1t = (f16*)p;  p += (size_t)2048 * 512 * 2;
  f16* o2t = (f16*)p;  p += (size_t)512 * 2048 * 2;
  f16* h1t = (f16*)p;  p += (size_t)512 * 1536 * 2;
  f16* h2t = (f16*)p;  p += (size_t)256 * 512 * 2;
  f16* h3t = (f16*)p;  p += (size_t)128 * 256 * 2;
  f16* entf = (f16*)p; p += (size_t)2000 * 512 * 2;
  f16* Hf   = (f16*)p; p += (size_t)32768 * 2048 * 2;  // 128 MB
  f16* bufA = (f16*)p; p += (size_t)32768 * 512 * 2;   // 32 MB
  f16* featf = (f16*)p; p += (size_t)512 * 1536 * 2;
  f16* z1h  = (f16*)p; p += (size_t)512 * 512 * 2;
  f16* z2h  = (f16*)p; p += (size_t)512 * 256 * 2;
  float* z3 = (float*)p; p += (size_t)512 * 128 * 4;
  // bufB overlays Hf's top half (per-level live region of Hf <= 64 MB then)
  f16* bufB = Hf + (size_t)32 * 1024 * 1024;

  // ---- prep
  transpose_cvt<<<dim3(1024 / 32, 2048 / 32), 256, 0, stream>>>(w1, w1t, 1024, 2048);
  transpose_cvt<<<dim3(2048 / 32, 512 / 32), 256, 0, stream>>>(w2, w2t, 2048, 512);
  transpose_cvt<<<dim3(512 / 32, 2048 / 32), 256, 0, stream>>>(o1, o1t, 512, 2048);
  transpose_cvt<<<dim3(2048 / 32, 512 / 32), 256, 0, stream>>>(o2, o2t, 2048, 512);
  transpose_cvt<<<dim3(1536 / 32, 512 / 32), 256, 0, stream>>>(h1, h1t, 1536, 512);
  transpose_cvt<<<dim3(512 / 32, 256 / 32), 256, 0, stream>>>(h2, h2t, 512, 256);
  transpose_cvt<<<dim3(256 / 32, 128 / 32), 256, 0, stream>>>(h3, h3t, 256, 128);
  cvt_f16<<<(2000 * 512) / 2048, 256, 0, stream>>>(ent_emb, entf);

  // ---- tree levels
  // L0 (M=32768): gather GEMM1 -> Hf (128 MB); GEMM2 -> bufA
  gemm256<1><<<dim3(8, 128), 512, 0, stream>>>(nullptr, w1t, b1, Hf, 2048,
                                               1024, leaf_idx, entf);
  gemm256<0><<<dim3(2, 128), 512, 0, stream>>>(Hf, w2t, b2, bufA, 512, 2048,
                                               nullptr, nullptr);
  // L1 (M=16384): GEMM1 -> Hf[0:64MB]; GEMM2 (128^2) -> bufB (@Hf+64MB)
  gemm256<0><<<dim3(8, 64), 512, 0, stream>>>(bufA, w1t, b1, Hf, 2048, 1024,
                                              nullptr, nullptr);
  gemm128<1, 0><<<dim3(4, 128), 256, 0, stream>>>(Hf, w2t, b2, bufB, 512, 2048);
  // L2 (M=8192): GEMM1 -> Hf[0:32MB]; GEMM2 -> bufA
  gemm256<0><<<dim3(8, 32), 512, 0, stream>>>(bufB, w1t, b1, Hf, 2048, 1024,
                                              nullptr, nullptr);
  gemm128<1, 0><<<dim3(4, 64), 256, 0, stream>>>(Hf, w2t, b2, bufA, 512, 2048);
  // L3 (M=4096)
  gemm128<1, 0><<<dim3(16, 32), 256, 0, stream>>>(bufA, w1t, b1, Hf, 2048, 1024);
  gemm128<1, 0><<<dim3(4, 32), 256, 0, stream>>>(Hf, w2t, b2, bufB, 512, 2048);
  // L4 (M=2048)
  gemm128<1, 0><<<dim3(16, 16), 256, 0, stream>>>(bufB, w1t, b1, Hf, 2048, 1024);
  gemm128<1, 0><<<dim3(4, 16), 256, 0, stream>>>(Hf, w2t, b2, bufA, 512, 2048);
  // L5 (M=1024)
  gemm128<1, 0><<<dim3(16, 8), 256, 0, stream>>>(bufA, w1t, b1, Hf, 2048, 1024);
  gemm128<1, 0><<<dim3(4, 8), 256, 0, stream>>>(Hf, w2t, b2, bufB, 512, 2048);

  // ---- one2one: relu(root@o1) -> tanh(..@o2); root = bufB [1024,512]
  gemm128<1, 0><<<dim3(16, 8), 256, 0, stream>>>(bufB, o1t, ob1, Hf, 2048, 512);
  gemm128<2, 0><<<dim3(4, 8), 256, 0, stream>>>(Hf, o2t, ob2, bufA, 512, 2048);

  // ---- head (f16 MFMA), root f16 = bufA [1024,512]
  build_feat_h<<<(512 * 1536) / 256, 256, 0, stream>>>(th_emb, bufA, featf);
  gemm128<1, 0><<<dim3(4, 4), 256, 0, stream>>>(featf, h1t, hb1, z1h, 512, 1536);
  gemm128<1, 0><<<dim3(2, 4), 256, 0, stream>>>(z1h, h2t, hb2, z2h, 256, 512);
  gemm128<1, 1><<<dim3(1, 4), 256, 0, stream>>>(z2h, h3t, hb3, z3, 128, 256);
  head_final<<<512, 64, 0, stream>>>(z3, h4, hb4, out);
}